// Round 2
// baseline (1821.728 us; speedup 1.0000x reference)
//
#include <hip/hip_runtime.h>
#include <stdint.h>

#define MAX_DEG   10
#define DEG_COUNT 30000
#define N_ATOMS   330000      // 11 * 30000
#define NF        128
#define BATCH     128

typedef __attribute__((ext_vector_type(8))) short bf16x8;   // 8 bf16 (4 VGPRs)
typedef __attribute__((ext_vector_type(4))) float f32x4;

__device__ __forceinline__ float bf2f(unsigned short h) {
  union { unsigned u; float f; } v; v.u = ((unsigned)h) << 16; return v.f;
}
__device__ __forceinline__ unsigned short f2bf(float f) {
  union { float f; unsigned u; } v; v.f = f;
  unsigned u = v.u;
  unsigned r = (u + 0x7fffu + ((u >> 16) & 1u)) >> 16;   // RNE
  return (unsigned short)r;
}

struct AdjPtrs { const int* p[10]; };

// ---------------------------------------------------------------------------
// K0: cast fp32 atoms -> bf16 copy (GEMM A-source + gather source, L3-resident)
// ---------------------------------------------------------------------------
__global__ __launch_bounds__(256) void k_cast(const float4* __restrict__ src,
                                              ushort4* __restrict__ dst) {
  size_t i = (size_t)blockIdx.x * 256 + threadIdx.x;   // one float4 -> ushort4
  float4 v = src[i];
  ushort4 o;
  o.x = f2bf(v.x); o.y = f2bf(v.y); o.z = f2bf(v.z); o.w = f2bf(v.w);
  dst[i] = o;
}

// ---------------------------------------------------------------------------
// K1a: build BcatT[d][n][k] (bf16), n,k in [0,256), from fp32 W.
// Virtual B[d][k][n]: k<128 -> neigh (Wrel | 0), k>=128 -> self (Wself | Wg)
// ---------------------------------------------------------------------------
__global__ __launch_bounds__(256) void k_build_b(const float* __restrict__ W,
                                                 unsigned short* __restrict__ BcatT) {
  int idx = blockIdx.x * 256 + threadIdx.x;
  if (idx >= 11 * 256 * 256) return;
  int d = idx >> 16;
  int rem = idx & 65535;
  int n = rem >> 8;
  int k = rem & 255;
  float v = 0.f;
  if (k < 128) {
    if (n < 128 && d >= 1) v = W[(2 * (d - 1)) * 16384 + k * 128 + n];
  } else {
    int ks = k - 128;
    if (n < 128) { int wi = (d >= 1) ? (2 * d - 1) : 20; v = W[wi * 16384 + ks * 128 + n]; }
    else         { int wi = (d >= 1) ? (20 + d)   : 31; v = W[wi * 16384 + ks * 128 + (n - 128)]; }
  }
  BcatT[idx] = f2bf(v);   // idx == d*65536 + n*256 + k
}

// K1b: biascat[d][n] f32: n<128 -> b_rel + b_self (activated), n>=128 -> b_gather
__global__ __launch_bounds__(256) void k_build_bias(const float* __restrict__ b,
                                                    float* __restrict__ biascat) {
  int idx = blockIdx.x * 256 + threadIdx.x;
  if (idx >= 11 * 256) return;
  int d = idx >> 8, n = idx & 255;
  float f;
  if (n < 128) {
    if (d >= 1) f = b[(2 * (d - 1)) * 128 + n] + b[(2 * d - 1) * 128 + n];
    else        f = b[20 * 128 + n];
  } else {
    int j = n - 128;
    f = (d >= 1) ? b[(20 + d) * 128 + j] : b[31 * 128 + j];
  }
  biascat[idx] = f;
}

// ---------------------------------------------------------------------------
// K2: neighbor sums from bf16 atom copy. One wave per atom row; lane = 2 cols.
// deg-0 rows written as zeros (ws is poisoned; B zero-block makes them inert).
// ---------------------------------------------------------------------------
__global__ __launch_bounds__(256) void k_nsum(const unsigned* __restrict__ atomsU,
                                              AdjPtrs adj,
                                              unsigned* __restrict__ nsumU) {
  int wave = threadIdx.x >> 6;
  int lane = threadIdx.x & 63;
  int row = blockIdx.x * 4 + wave;
  if (row >= N_ATOMS) return;
  int d = row / DEG_COUNT;
  if (d == 0) { nsumU[row * 64 + lane] = 0u; return; }
  int r = row - d * DEG_COUNT;
  const int* a = adj.p[d - 1];
  float s0 = 0.f, s1 = 0.f;
  for (int j = 0; j < d; ++j) {
    int nbr = a[r * d + j];
    unsigned x = atomsU[nbr * 64 + lane];
    s0 += bf2f((unsigned short)(x & 0xffff));
    s1 += bf2f((unsigned short)(x >> 16));
  }
  nsumU[row * 64 + lane] = (unsigned)f2bf(s0) | ((unsigned)f2bf(s1) << 16);
}

// ---------------------------------------------------------------------------
// K3: tiled MFMA GEMM. Per block: 128 rows of one degree bucket x 128 output
// cols (nt=0 -> activated fp32 to d_out, nt=1 -> gathered bf16 ws), K=256.
// A virtual = [nsum(128) | atomsBf(128)]. LDS rows padded to 72 shorts.
// ---------------------------------------------------------------------------
__global__ __launch_bounds__(256, 2) void k_gemm(
    const unsigned short* __restrict__ atomsBf,
    const unsigned short* __restrict__ nsum,
    const unsigned short* __restrict__ BcatT,    // [11][256][256] n-major
    const float* __restrict__ biascat,           // [11][256]
    float* __restrict__ out0,                    // activated pre-norm (= d_out, fp32)
    unsigned short* __restrict__ gath)           // gathered ws (bf16)
{
  const int d = blockIdx.y;
  const int rowTile = blockIdx.x;
  const int nt = blockIdx.z;
  const int tid = threadIdx.x;
  const int lane = tid & 63;
  const int wave = tid >> 6;
  const int waveRow = wave & 1, waveCol = wave >> 1;

  __shared__ unsigned short As[128 * 72];
  __shared__ unsigned short Bs[128 * 72];

  f32x4 acc[4][4];
#pragma unroll
  for (int i = 0; i < 4; i++)
#pragma unroll
    for (int j = 0; j < 4; j++) acc[i][j] = (f32x4){0.f, 0.f, 0.f, 0.f};

  const unsigned short* Bd = BcatT + d * 65536 + (nt * 128) * 256;

  for (int k0 = 0; k0 < 4; ++k0) {
    uint4 aReg[4], bReg[4];
#pragma unroll
    for (int c = 0; c < 4; ++c) {
      int flat = c * 256 + tid;
      int rl = flat >> 3;
      int col8 = (flat & 7) << 3;
      int rb = rowTile * 128 + rl; if (rb > DEG_COUNT - 1) rb = DEG_COUNT - 1;
      int grow = d * DEG_COUNT + rb;
      const unsigned short* srcA = (k0 < 2) ? (nsum + (size_t)grow * 128 + k0 * 64 + col8)
                                            : (atomsBf + (size_t)grow * 128 + (k0 - 2) * 64 + col8);
      aReg[c] = *(const uint4*)srcA;
      bReg[c] = *(const uint4*)(Bd + rl * 256 + k0 * 64 + col8);
    }
    __syncthreads();
#pragma unroll
    for (int c = 0; c < 4; ++c) {
      int flat = c * 256 + tid;
      int rl = flat >> 3;
      int col8 = (flat & 7) << 3;
      *(uint4*)(&As[rl * 72 + col8]) = aReg[c];
      *(uint4*)(&Bs[rl * 72 + col8]) = bReg[c];
    }
    __syncthreads();
#pragma unroll
    for (int ks = 0; ks < 2; ++ks) {
      bf16x8 afrag[4], bfrag[4];
      int kofs = ks * 32 + (lane >> 4) * 8;
      int m16 = lane & 15;
#pragma unroll
      for (int rt = 0; rt < 4; ++rt)
        afrag[rt] = *(const bf16x8*)(&As[(waveRow * 64 + rt * 16 + m16) * 72 + kofs]);
#pragma unroll
      for (int ct = 0; ct < 4; ++ct)
        bfrag[ct] = *(const bf16x8*)(&Bs[(waveCol * 64 + ct * 16 + m16) * 72 + kofs]);
#pragma unroll
      for (int rt = 0; rt < 4; ++rt)
#pragma unroll
        for (int ct = 0; ct < 4; ++ct)
          acc[rt][ct] = __builtin_amdgcn_mfma_f32_16x16x32_bf16(afrag[rt], bfrag[ct], acc[rt][ct], 0, 0, 0);
    }
  }

  // epilogue: bias add; C layout: col=lane&15, row=(lane>>4)*4+reg
  int m16 = lane & 15, quad = lane >> 4;
#pragma unroll
  for (int ct = 0; ct < 4; ++ct) {
    int col = waveCol * 64 + ct * 16 + m16;
    float bias = biascat[d * 256 + nt * 128 + col];
#pragma unroll
    for (int rt = 0; rt < 4; ++rt) {
#pragma unroll
      for (int r = 0; r < 4; ++r) {
        int rb = rowTile * 128 + waveRow * 64 + rt * 16 + quad * 4 + r;
        if (rb < DEG_COUNT) {
          size_t grow = (size_t)(d * DEG_COUNT + rb);
          float v = acc[rt][ct][r] + bias;
          if (nt == 0) out0[grow * 128 + col] = v;
          else         gath[grow * 128 + col] = f2bf(v);
        }
      }
    }
  }
}

// ---------------------------------------------------------------------------
// K4: in-place row LayerNorm of activated (out0, fp32), + per-block
// segment-max partials of normalized values (LDS, float-as-int max trick).
// ---------------------------------------------------------------------------
__global__ __launch_bounds__(256) void k_norm_max(
    float2* __restrict__ xnV,               // out0 as float2; lane = cols 2l,2l+1
    const int* __restrict__ membership,
    const float* __restrict__ gamma,
    const float* __restrict__ beta,
    float* __restrict__ maxpart)            // [gridDim.x][128*128]
{
  __shared__ int pmax[BATCH * 128];
  int tid = threadIdx.x;
  for (int i = tid; i < BATCH * 128; i += 256) pmax[i] = 0xFF800000;  // -inf
  __syncthreads();
  int wave = tid >> 6, lane = tid & 63;
  float g0 = gamma[2 * lane], g1 = gamma[2 * lane + 1];
  float b0 = beta[2 * lane],  b1 = beta[2 * lane + 1];
  const int rowsPerBlock = (N_ATOMS + gridDim.x - 1) / gridDim.x;
  int r0 = blockIdx.x * rowsPerBlock;
  int r1 = min(r0 + rowsPerBlock, N_ATOMS);
  for (int r = r0 + wave; r < r1; r += 4) {
    float2 x = xnV[(size_t)r * 64 + lane];
    float a0 = x.x, a1 = x.y;
    float s = a0 + a1, q = a0 * a0 + a1 * a1;
#pragma unroll
    for (int off = 32; off >= 1; off >>= 1) {
      s += __shfl_xor(s, off, 64);
      q += __shfl_xor(q, off, 64);
    }
    float mean = s * (1.0f / 128.0f);
    float var = q * (1.0f / 128.0f) - mean * mean;
    float inv = 1.0f / (sqrtf(var + 1e-5f) + 1e-5f);   // ref: sqrt(var+eps)+eps
    float xn0 = g0 * ((a0 - mean) * inv) + b0;
    float xn1 = g1 * ((a1 - mean) * inv) + b1;
    xnV[(size_t)r * 64 + lane] = make_float2(xn0, xn1);
    int m = membership[r];
    int idx = m * 128 + lane * 2;
    if (xn0 >= 0.f) atomicMax(&pmax[idx], __float_as_int(xn0));
    else            atomicMin((unsigned*)&pmax[idx], __float_as_uint(xn0));
    if (xn1 >= 0.f) atomicMax(&pmax[idx + 1], __float_as_int(xn1));
    else            atomicMin((unsigned*)&pmax[idx + 1], __float_as_uint(xn1));
  }
  __syncthreads();
  float* dst = maxpart + (size_t)blockIdx.x * (BATCH * 128);
  for (int i = tid; i < BATCH * 128; i += 256) dst[i] = __int_as_float(pmax[i]);
}

// K5: per-block segment-sum partials of gathered (bf16 ws).
__global__ __launch_bounds__(256) void k_segsum(
    const unsigned* __restrict__ gathU,
    const int* __restrict__ membership,
    float* __restrict__ sumpart)
{
  __shared__ float psum[BATCH * 128];
  int tid = threadIdx.x;
  for (int i = tid; i < BATCH * 128; i += 256) psum[i] = 0.f;
  __syncthreads();
  int wave = tid >> 6, lane = tid & 63;
  const int rowsPerBlock = (N_ATOMS + gridDim.x - 1) / gridDim.x;
  int r0 = blockIdx.x * rowsPerBlock;
  int r1 = min(r0 + rowsPerBlock, N_ATOMS);
  for (int r = r0 + wave; r < r1; r += 4) {
    unsigned x = gathU[(size_t)r * 64 + lane];
    int m = membership[r];
    atomicAdd(&psum[m * 128 + lane * 2],     bf2f((unsigned short)(x & 0xffff)));
    atomicAdd(&psum[m * 128 + lane * 2 + 1], bf2f((unsigned short)(x >> 16)));
  }
  __syncthreads();
  float* dst = sumpart + (size_t)blockIdx.x * (BATCH * 128);
  for (int i = tid; i < BATCH * 128; i += 256) dst[i] = psum[i];
}

// K6: reduce partials -> atom_gather, norm -> yn (out1); max -> g (out2). fp32.
__global__ __launch_bounds__(128) void k_final(
    const float* __restrict__ sumpart,
    const float* __restrict__ maxpart,
    const float* __restrict__ gamma,
    const float* __restrict__ beta,
    float* __restrict__ out1,
    float* __restrict__ out2,
    int NP)
{
  int m = blockIdx.x;
  int j = threadIdx.x;
  float s = 0.f, mx = -INFINITY;
  for (int p = 0; p < NP; ++p) {
    s  += sumpart[(size_t)p * 16384 + m * 128 + j];
    mx = fmaxf(mx, maxpart[(size_t)p * 16384 + m * 128 + j]);
  }
  out2[m * 128 + j] = mx;

  float ws_ = s, wq = s * s;
#pragma unroll
  for (int off = 32; off >= 1; off >>= 1) {
    ws_ += __shfl_xor(ws_, off, 64);
    wq  += __shfl_xor(wq, off, 64);
  }
  __shared__ float red[4];
  int wave = j >> 6, lane = j & 63;
  if (lane == 0) { red[wave * 2] = ws_; red[wave * 2 + 1] = wq; }
  __syncthreads();
  float S = red[0] + red[2], Q = red[1] + red[3];
  float mean = S * (1.f / 128.f);
  float var = Q * (1.f / 128.f) - mean * mean;
  float inv = 1.f / (sqrtf(var + 1e-5f) + 1e-5f);
  float yn = gamma[j] * ((s - mean) * inv) + beta[j];
  out1[m * 128 + j] = yn;
}

// ---------------------------------------------------------------------------
extern "C" void kernel_launch(void* const* d_in, const int* in_sizes, int n_in,
                              void* d_out, int out_size, void* d_ws, size_t ws_size,
                              hipStream_t stream) {
  const float* atoms = (const float*)d_in[0];
  // d_in[1] = deg_slice (unused; buckets are static)
  const int* membership = (const int*)d_in[2];
  AdjPtrs adj;
  for (int i = 0; i < 10; ++i) adj.p[i] = (const int*)d_in[3 + i];
  const float* W     = (const float*)d_in[13];
  const float* b     = (const float*)d_in[14];
  const float* gamma = (const float*)d_in[15];
  const float* beta  = (const float*)d_in[16];

  char* ws = (char*)d_ws;
  size_t off = 0;
  unsigned short* atomsBf = (unsigned short*)(ws + off); off += (size_t)N_ATOMS * 128 * 2;
  unsigned short* nsum    = (unsigned short*)(ws + off); off += (size_t)N_ATOMS * 128 * 2;
  unsigned short* gath    = (unsigned short*)(ws + off); off += (size_t)N_ATOMS * 128 * 2;
  unsigned short* BcatT   = (unsigned short*)(ws + off); off += (size_t)11 * 256 * 256 * 2;
  float* biascat          = (float*)(ws + off);          off += (size_t)11 * 256 * 4;
  const int NP = 128;
  float* sumpart          = (float*)(ws + off);          off += (size_t)NP * 16384 * 4;
  float* maxpart          = (float*)(ws + off);          off += (size_t)NP * 16384 * 4;

  float* out0 = (float*)d_out;
  float* out1 = out0 + (size_t)N_ATOMS * 128;
  float* out2 = out1 + 16384;

  hipLaunchKernelGGL(k_cast, dim3(N_ATOMS * 128 / 4 / 256), dim3(256), 0, stream,
                     (const float4*)atoms, (ushort4*)atomsBf);
  hipLaunchKernelGGL(k_build_b, dim3((11 * 256 * 256 + 255) / 256), dim3(256), 0, stream, W, BcatT);
  hipLaunchKernelGGL(k_build_bias, dim3((11 * 256 + 255) / 256), dim3(256), 0, stream, b, biascat);
  hipLaunchKernelGGL(k_nsum, dim3(N_ATOMS / 4), dim3(256), 0, stream,
                     (const unsigned*)atomsBf, adj, (unsigned*)nsum);
  hipLaunchKernelGGL(k_gemm, dim3(235, 11, 2), dim3(256), 0, stream,
                     atomsBf, nsum, BcatT, biascat, out0, gath);
  hipLaunchKernelGGL(k_norm_max, dim3(NP), dim3(256), 0, stream,
                     (float2*)out0, membership, gamma, beta, maxpart);
  hipLaunchKernelGGL(k_segsum, dim3(NP), dim3(256), 0, stream,
                     (const unsigned*)gath, membership, sumpart);
  hipLaunchKernelGGL(k_final, dim3(128), dim3(128), 0, stream,
                     sumpart, maxpart, gamma, beta, out1, out2, NP);
}

// Round 4
// 1214.712 us; speedup vs baseline: 1.4997x; 1.4997x over previous
//
#include <hip/hip_runtime.h>
#include <stdint.h>

#define MAX_DEG   10
#define DEG_COUNT 30000
#define N_ATOMS   330000      // 11 * 30000
#define NF        128
#define BATCH     128

typedef __attribute__((ext_vector_type(8))) short bf16x8;   // 8 bf16 (4 VGPRs)
typedef __attribute__((ext_vector_type(4))) float f32x4;

__device__ __forceinline__ float bf2f(unsigned short h) {
  union { unsigned u; float f; } v; v.u = ((unsigned)h) << 16; return v.f;
}
__device__ __forceinline__ unsigned short f2bf(float f) {
  union { float f; unsigned u; } v; v.f = f;
  unsigned u = v.u;
  unsigned r = (u + 0x7fffu + ((u >> 16) & 1u)) >> 16;   // RNE
  return (unsigned short)r;
}

struct AdjPtrs { const int* p[10]; };

#define NEG_INF_BITS 0xFF800000

// ---------------------------------------------------------------------------
// K_init: zero gsum, -inf gmax (ws is re-poisoned before every launch).
// ---------------------------------------------------------------------------
__global__ __launch_bounds__(256) void k_init(float* __restrict__ gsum,
                                              int* __restrict__ gmax) {
  int i = blockIdx.x * 256 + threadIdx.x;
  if (i < BATCH * 128) { gsum[i] = 0.f; gmax[i] = (int)NEG_INF_BITS; }
}

// ---------------------------------------------------------------------------
// K0: cast fp32 atoms -> bf16 copy (GEMM A-source + gather source, L3-resident)
// ---------------------------------------------------------------------------
__global__ __launch_bounds__(256) void k_cast(const float4* __restrict__ src,
                                              ushort4* __restrict__ dst) {
  size_t i = (size_t)blockIdx.x * 256 + threadIdx.x;   // one float4 -> ushort4
  float4 v = src[i];
  ushort4 o;
  o.x = f2bf(v.x); o.y = f2bf(v.y); o.z = f2bf(v.z); o.w = f2bf(v.w);
  dst[i] = o;
}

// ---------------------------------------------------------------------------
// K1a: build BcatT[d][n][k] (bf16), n,k in [0,256), from fp32 W.
// Virtual B[d][k][n]: k<128 -> neigh (Wrel | 0), k>=128 -> self (Wself | Wg)
// ---------------------------------------------------------------------------
__global__ __launch_bounds__(256) void k_build_b(const float* __restrict__ W,
                                                 unsigned short* __restrict__ BcatT) {
  int idx = blockIdx.x * 256 + threadIdx.x;
  if (idx >= 11 * 256 * 256) return;
  int d = idx >> 16;
  int rem = idx & 65535;
  int n = rem >> 8;
  int k = rem & 255;
  float v = 0.f;
  if (k < 128) {
    if (n < 128 && d >= 1) v = W[(2 * (d - 1)) * 16384 + k * 128 + n];
  } else {
    int ks = k - 128;
    if (n < 128) { int wi = (d >= 1) ? (2 * d - 1) : 20; v = W[wi * 16384 + ks * 128 + n]; }
    else         { int wi = (d >= 1) ? (20 + d)   : 31; v = W[wi * 16384 + ks * 128 + (n - 128)]; }
  }
  BcatT[idx] = f2bf(v);   // idx == d*65536 + n*256 + k
}

// K1b: biascat[d][n] f32: n<128 -> b_rel + b_self (activated), n>=128 -> b_gather
__global__ __launch_bounds__(256) void k_build_bias(const float* __restrict__ b,
                                                    float* __restrict__ biascat) {
  int idx = blockIdx.x * 256 + threadIdx.x;
  if (idx >= 11 * 256) return;
  int d = idx >> 8, n = idx & 255;
  float f;
  if (n < 128) {
    if (d >= 1) f = b[(2 * (d - 1)) * 128 + n] + b[(2 * d - 1) * 128 + n];
    else        f = b[20 * 128 + n];
  } else {
    int j = n - 128;
    f = (d >= 1) ? b[(20 + d) * 128 + j] : b[31 * 128 + j];
  }
  biascat[idx] = f;
}

// ---------------------------------------------------------------------------
// K2: neighbor sums from bf16 atom copy. One wave per atom row; lane = 2 cols.
// deg-0 rows written as zeros (ws is poisoned; B zero-block makes them inert).
// ---------------------------------------------------------------------------
__global__ __launch_bounds__(256) void k_nsum(const unsigned* __restrict__ atomsU,
                                              AdjPtrs adj,
                                              unsigned* __restrict__ nsumU) {
  int wave = threadIdx.x >> 6;
  int lane = threadIdx.x & 63;
  int row = blockIdx.x * 4 + wave;
  if (row >= N_ATOMS) return;
  int d = row / DEG_COUNT;
  if (d == 0) { nsumU[row * 64 + lane] = 0u; return; }
  int r = row - d * DEG_COUNT;
  const int* a = adj.p[d - 1];
  float s0 = 0.f, s1 = 0.f;
  for (int j = 0; j < d; ++j) {
    int nbr = a[r * d + j];
    unsigned x = atomsU[nbr * 64 + lane];
    s0 += bf2f((unsigned short)(x & 0xffff));
    s1 += bf2f((unsigned short)(x >> 16));
  }
  nsumU[row * 64 + lane] = (unsigned)f2bf(s0) | ((unsigned)f2bf(s1) << 16);
}

// ---------------------------------------------------------------------------
// K3: tiled MFMA GEMM. Per block: 128 rows of one degree bucket x 128 output
// cols (nt=0 -> activated fp32 to d_out, nt=1 -> gathered bf16 ws), K=256.
// A virtual = [nsum(128) | atomsBf(128)]. LDS rows padded to 72 shorts.
// ---------------------------------------------------------------------------
__global__ __launch_bounds__(256, 2) void k_gemm(
    const unsigned short* __restrict__ atomsBf,
    const unsigned short* __restrict__ nsum,
    const unsigned short* __restrict__ BcatT,    // [11][256][256] n-major
    const float* __restrict__ biascat,           // [11][256]
    float* __restrict__ out0,                    // activated pre-norm (= d_out, fp32)
    unsigned short* __restrict__ gath)           // gathered ws (bf16)
{
  const int d = blockIdx.y;
  const int rowTile = blockIdx.x;
  const int nt = blockIdx.z;
  const int tid = threadIdx.x;
  const int lane = tid & 63;
  const int wave = tid >> 6;
  const int waveRow = wave & 1, waveCol = wave >> 1;

  __shared__ unsigned short As[128 * 72];
  __shared__ unsigned short Bs[128 * 72];

  f32x4 acc[4][4];
#pragma unroll
  for (int i = 0; i < 4; i++)
#pragma unroll
    for (int j = 0; j < 4; j++) acc[i][j] = (f32x4){0.f, 0.f, 0.f, 0.f};

  const unsigned short* Bd = BcatT + d * 65536 + (nt * 128) * 256;

  for (int k0 = 0; k0 < 4; ++k0) {
    uint4 aReg[4], bReg[4];
#pragma unroll
    for (int c = 0; c < 4; ++c) {
      int flat = c * 256 + tid;
      int rl = flat >> 3;
      int col8 = (flat & 7) << 3;
      int rb = rowTile * 128 + rl; if (rb > DEG_COUNT - 1) rb = DEG_COUNT - 1;
      int grow = d * DEG_COUNT + rb;
      const unsigned short* srcA = (k0 < 2) ? (nsum + (size_t)grow * 128 + k0 * 64 + col8)
                                            : (atomsBf + (size_t)grow * 128 + (k0 - 2) * 64 + col8);
      aReg[c] = *(const uint4*)srcA;
      bReg[c] = *(const uint4*)(Bd + rl * 256 + k0 * 64 + col8);
    }
    __syncthreads();
#pragma unroll
    for (int c = 0; c < 4; ++c) {
      int flat = c * 256 + tid;
      int rl = flat >> 3;
      int col8 = (flat & 7) << 3;
      *(uint4*)(&As[rl * 72 + col8]) = aReg[c];
      *(uint4*)(&Bs[rl * 72 + col8]) = bReg[c];
    }
    __syncthreads();
#pragma unroll
    for (int ks = 0; ks < 2; ++ks) {
      bf16x8 afrag[4], bfrag[4];
      int kofs = ks * 32 + (lane >> 4) * 8;
      int m16 = lane & 15;
#pragma unroll
      for (int rt = 0; rt < 4; ++rt)
        afrag[rt] = *(const bf16x8*)(&As[(waveRow * 64 + rt * 16 + m16) * 72 + kofs]);
#pragma unroll
      for (int ct = 0; ct < 4; ++ct)
        bfrag[ct] = *(const bf16x8*)(&Bs[(waveCol * 64 + ct * 16 + m16) * 72 + kofs]);
#pragma unroll
      for (int rt = 0; rt < 4; ++rt)
#pragma unroll
        for (int ct = 0; ct < 4; ++ct)
          acc[rt][ct] = __builtin_amdgcn_mfma_f32_16x16x32_bf16(afrag[rt], bfrag[ct], acc[rt][ct], 0, 0, 0);
    }
  }

  // epilogue: bias add; C layout: col=lane&15, row=(lane>>4)*4+reg
  int m16 = lane & 15, quad = lane >> 4;
#pragma unroll
  for (int ct = 0; ct < 4; ++ct) {
    int col = waveCol * 64 + ct * 16 + m16;
    float bias = biascat[d * 256 + nt * 128 + col];
#pragma unroll
    for (int rt = 0; rt < 4; ++rt) {
#pragma unroll
      for (int r = 0; r < 4; ++r) {
        int rb = rowTile * 128 + waveRow * 64 + rt * 16 + quad * 4 + r;
        if (rb < DEG_COUNT) {
          size_t grow = (size_t)(d * DEG_COUNT + rb);
          float v = acc[rt][ct][r] + bias;
          if (nt == 0) out0[grow * 128 + col] = v;
          else         gath[grow * 128 + col] = f2bf(v);
        }
      }
    }
  }
}

// ---------------------------------------------------------------------------
// K4: in-place row LayerNorm of activated (out0, fp32) with 2-row ILP, +
// per-block LDS segment-max, merged into global gmax via monotonic-int atomics.
// 512 blocks x 512 threads; 64 KB LDS -> 2 blocks/CU, 16 waves/CU.
// ---------------------------------------------------------------------------
__global__ __launch_bounds__(512) void k_norm_max(
    float2* __restrict__ xnV,               // out0 as float2; lane = cols 2l,2l+1
    const int* __restrict__ membership,
    const float* __restrict__ gamma,
    const float* __restrict__ beta,
    int* __restrict__ gmax)                 // [BATCH*128] monotonic float-bits
{
  __shared__ int pmax[BATCH * 128];
  int tid = threadIdx.x;
  for (int i = tid; i < BATCH * 128; i += 512) pmax[i] = (int)NEG_INF_BITS;
  __syncthreads();
  int wave = tid >> 6, lane = tid & 63;
  float g0 = gamma[2 * lane], g1 = gamma[2 * lane + 1];
  float b0 = beta[2 * lane],  b1 = beta[2 * lane + 1];
  const int rowsPerBlock = (N_ATOMS + gridDim.x - 1) / gridDim.x;
  int r0 = blockIdx.x * rowsPerBlock;
  int r1 = min(r0 + rowsPerBlock, N_ATOMS);
  for (int rA = r0 + wave * 2; rA < r1; rA += 16) {
    bool hasB = (rA + 1 < r1);
    int rB = hasB ? rA + 1 : rA;
    float2 xA = xnV[(size_t)rA * 64 + lane];
    float2 xB = xnV[(size_t)rB * 64 + lane];
    float sA = xA.x + xA.y, qA = xA.x * xA.x + xA.y * xA.y;
    float sB = xB.x + xB.y, qB = xB.x * xB.x + xB.y * xB.y;
#pragma unroll
    for (int off = 32; off >= 1; off >>= 1) {
      sA += __shfl_xor(sA, off, 64);
      qA += __shfl_xor(qA, off, 64);
      sB += __shfl_xor(sB, off, 64);
      qB += __shfl_xor(qB, off, 64);
    }
    float meanA = sA * (1.0f / 128.0f);
    float varA = qA * (1.0f / 128.0f) - meanA * meanA;
    float invA = 1.0f / (sqrtf(varA + 1e-5f) + 1e-5f);   // ref: sqrt(var+eps)+eps
    float meanB = sB * (1.0f / 128.0f);
    float varB = qB * (1.0f / 128.0f) - meanB * meanB;
    float invB = 1.0f / (sqrtf(varB + 1e-5f) + 1e-5f);
    float a0 = g0 * ((xA.x - meanA) * invA) + b0;
    float a1 = g1 * ((xA.y - meanA) * invA) + b1;
    float c0 = g0 * ((xB.x - meanB) * invB) + b0;
    float c1 = g1 * ((xB.y - meanB) * invB) + b1;
    xnV[(size_t)rA * 64 + lane] = make_float2(a0, a1);
    int mA = membership[rA];
    int idxA = mA * 128 + lane * 2;
    if (a0 >= 0.f) atomicMax(&pmax[idxA], __float_as_int(a0));
    else           atomicMin((unsigned*)&pmax[idxA], __float_as_uint(a0));
    if (a1 >= 0.f) atomicMax(&pmax[idxA + 1], __float_as_int(a1));
    else           atomicMin((unsigned*)&pmax[idxA + 1], __float_as_uint(a1));
    if (hasB) {
      xnV[(size_t)rB * 64 + lane] = make_float2(c0, c1);
      int mB = membership[rB];
      int idxB = mB * 128 + lane * 2;
      if (c0 >= 0.f) atomicMax(&pmax[idxB], __float_as_int(c0));
      else           atomicMin((unsigned*)&pmax[idxB], __float_as_uint(c0));
      if (c1 >= 0.f) atomicMax(&pmax[idxB + 1], __float_as_int(c1));
      else           atomicMin((unsigned*)&pmax[idxB + 1], __float_as_uint(c1));
    }
  }
  __syncthreads();
  for (int i = tid; i < BATCH * 128; i += 512) {
    int v = pmax[i];
    if (v != (int)NEG_INF_BITS) {
      if (v >= 0) atomicMax(&gmax[i], v);
      else        atomicMin((unsigned*)&gmax[i], (unsigned)v);
    }
  }
}

// K5: per-block LDS segment-sum of gathered (bf16 ws), merged via atomicAdd.
__global__ __launch_bounds__(512) void k_segsum(
    const unsigned* __restrict__ gathU,
    const int* __restrict__ membership,
    float* __restrict__ gsum)
{
  __shared__ float psum[BATCH * 128];
  int tid = threadIdx.x;
  for (int i = tid; i < BATCH * 128; i += 512) psum[i] = 0.f;
  __syncthreads();
  int wave = tid >> 6, lane = tid & 63;
  const int rowsPerBlock = (N_ATOMS + gridDim.x - 1) / gridDim.x;
  int r0 = blockIdx.x * rowsPerBlock;
  int r1 = min(r0 + rowsPerBlock, N_ATOMS);
  for (int r = r0 + wave; r < r1; r += 8) {
    unsigned x = gathU[(size_t)r * 64 + lane];
    int m = membership[r];
    atomicAdd(&psum[m * 128 + lane * 2],     bf2f((unsigned short)(x & 0xffff)));
    atomicAdd(&psum[m * 128 + lane * 2 + 1], bf2f((unsigned short)(x >> 16)));
  }
  __syncthreads();
  for (int i = tid; i < BATCH * 128; i += 512) {
    float v = psum[i];
    if (v != 0.f) atomicAdd(&gsum[i], v);
  }
}

// K6: norm gsum -> yn (out1); gmax -> g (out2). fp32.
__global__ __launch_bounds__(128) void k_final(
    const float* __restrict__ gsum,
    const int* __restrict__ gmax,
    const float* __restrict__ gamma,
    const float* __restrict__ beta,
    float* __restrict__ out1,
    float* __restrict__ out2)
{
  int m = blockIdx.x;
  int j = threadIdx.x;
  float s = gsum[m * 128 + j];
  out2[m * 128 + j] = __int_as_float(gmax[m * 128 + j]);

  float ws_ = s, wq = s * s;
#pragma unroll
  for (int off = 32; off >= 1; off >>= 1) {
    ws_ += __shfl_xor(ws_, off, 64);
    wq  += __shfl_xor(wq, off, 64);
  }
  __shared__ float red[4];
  int wave = j >> 6, lane = j & 63;
  if (lane == 0) { red[wave * 2] = ws_; red[wave * 2 + 1] = wq; }
  __syncthreads();
  float S = red[0] + red[2], Q = red[1] + red[3];
  float mean = S * (1.f / 128.f);
  float var = Q * (1.f / 128.f) - mean * mean;
  float inv = 1.f / (sqrtf(var + 1e-5f) + 1e-5f);
  float yn = gamma[j] * ((s - mean) * inv) + beta[j];
  out1[m * 128 + j] = yn;
}

// ---------------------------------------------------------------------------
extern "C" void kernel_launch(void* const* d_in, const int* in_sizes, int n_in,
                              void* d_out, int out_size, void* d_ws, size_t ws_size,
                              hipStream_t stream) {
  const float* atoms = (const float*)d_in[0];
  // d_in[1] = deg_slice (unused; buckets are static)
  const int* membership = (const int*)d_in[2];
  AdjPtrs adj;
  for (int i = 0; i < 10; ++i) adj.p[i] = (const int*)d_in[3 + i];
  const float* W     = (const float*)d_in[13];
  const float* b     = (const float*)d_in[14];
  const float* gamma = (const float*)d_in[15];
  const float* beta  = (const float*)d_in[16];

  char* ws = (char*)d_ws;
  size_t off = 0;
  unsigned short* atomsBf = (unsigned short*)(ws + off); off += (size_t)N_ATOMS * 128 * 2;
  unsigned short* nsum    = (unsigned short*)(ws + off); off += (size_t)N_ATOMS * 128 * 2;
  unsigned short* gath    = (unsigned short*)(ws + off); off += (size_t)N_ATOMS * 128 * 2;
  unsigned short* BcatT   = (unsigned short*)(ws + off); off += (size_t)11 * 256 * 256 * 2;
  float* biascat          = (float*)(ws + off);          off += (size_t)11 * 256 * 4;
  float* gsum             = (float*)(ws + off);          off += (size_t)BATCH * 128 * 4;
  int*   gmax             = (int*)(ws + off);            off += (size_t)BATCH * 128 * 4;

  float* out0 = (float*)d_out;
  float* out1 = out0 + (size_t)N_ATOMS * 128;
  float* out2 = out1 + 16384;

  hipLaunchKernelGGL(k_init, dim3((BATCH * 128 + 255) / 256), dim3(256), 0, stream, gsum, gmax);
  hipLaunchKernelGGL(k_cast, dim3(N_ATOMS * 128 / 4 / 256), dim3(256), 0, stream,
                     (const float4*)atoms, (ushort4*)atomsBf);
  hipLaunchKernelGGL(k_build_b, dim3((11 * 256 * 256 + 255) / 256), dim3(256), 0, stream, W, BcatT);
  hipLaunchKernelGGL(k_build_bias, dim3((11 * 256 + 255) / 256), dim3(256), 0, stream, b, biascat);
  hipLaunchKernelGGL(k_nsum, dim3(N_ATOMS / 4), dim3(256), 0, stream,
                     (const unsigned*)atomsBf, adj, (unsigned*)nsum);
  hipLaunchKernelGGL(k_gemm, dim3(235, 11, 2), dim3(256), 0, stream,
                     atomsBf, nsum, BcatT, biascat, out0, gath);
  hipLaunchKernelGGL(k_norm_max, dim3(512), dim3(512), 0, stream,
                     (float2*)out0, membership, gamma, beta, gmax);
  hipLaunchKernelGGL(k_segsum, dim3(512), dim3(512), 0, stream,
                     (const unsigned*)gath, membership, gsum);
  hipLaunchKernelGGL(k_final, dim3(128), dim3(128), 0, stream,
                     gsum, gmax, gamma, beta, out1, out2);
}